// Round 4
// baseline (43.291 us; speedup 1.0000x reference)
//
#include <hip/hip_runtime.h>

#define NQ 10
#define EMBED 1024
#define ROWS_PER_BLOCK 32
#define BLOCK 256            // 4 waves; each wave does 8 rows (2 per lane)

// ---------------------------------------------------------------------------
// Closed-form ev (validated R1-R3, passing at absmax 2e-3):
// conjugate circuit by H^10 -> RX gates become diagonal phases, CNOT ring
// becomes reversed ring sigma.  <Z_q> collapses to a trig polynomial:
//   ev_q = sum_{S subset u_q, T=sigma^T S subset v_q} i^(|T|+|S|)
//          prod_{T} sinA prod_{v\T} cosA * prod_{S} sinB prod_{u\S} cosB
// Odd-parity terms are imaginary and cancel -> filtered at constexpr time.
// ---------------------------------------------------------------------------

constexpr int kPop(int x) { int c = 0; for (int i = 0; i < 10; ++i) c += (x >> i) & 1; return c; }

constexpr int sigma_map(int a) {
    int b = 0;
    for (int i = 0; i < 9; ++i) b |= (((a >> i) & 1) ^ ((a >> (i + 1)) & 1)) << i;
    b |= (((a >> 9) & 1) ^ ((a >> 0) & 1) ^ ((a >> 1) & 1)) << 9;
    return b;
}

#define MAXT 40
struct Terms {
    int nt[NQ];
    int vm[NQ];
    int um[NQ];
    unsigned short tm[NQ][MAXT];
    unsigned short sm[NQ][MAXT];
    float sg[NQ][MAXT];
};

constexpr Terms gen_terms() {
    Terms t{};
    int inv_e[NQ] = {};
    for (int a = 0; a < 1024; ++a) {
        const int s = sigma_map(a);
        for (int q = 0; q < NQ; ++q) if (s == (1 << q)) inv_e[q] = a;
    }
    for (int q = 0; q < NQ; ++q) {
        const int u = inv_e[q];
        int v = 0;
        for (int w = 0; w < NQ; ++w) if ((u >> w) & 1) v ^= inv_e[w];
        t.um[q] = u; t.vm[q] = v;
        int n = 0;
        int S = 0;
        while (true) {
            int T = (((S >> 0) ^ (S >> 9)) & 1)
                  | ((((S >> 0) ^ (S >> 1) ^ (S >> 9)) & 1) << 1);
            for (int j = 2; j < 10; ++j) T |= ((((S >> (j - 1)) ^ (S >> j)) & 1) << j);
            if ((T & ~v) == 0) {
                const int p = kPop(T) + kPop(S);
                if (!(p & 1)) {
                    t.tm[q][n] = (unsigned short)T;
                    t.sm[q][n] = (unsigned short)S;
                    t.sg[q][n] = (p & 2) ? -1.f : 1.f;
                    ++n;
                }
            }
            if (S == u) break;
            S = (S - u) & u;
        }
        t.nt[q] = n;
    }
    return t;
}

constexpr Terms TT = gen_terms();

extern "C" __global__ __launch_bounds__(BLOCK, 3)
void ffq_kernel(const float* __restrict__ x, const float* __restrict__ W1,
                const float* __restrict__ b1, const float* __restrict__ qw,
                const float* __restrict__ W2, const float* __restrict__ b2,
                float* __restrict__ out)
{
    __shared__ float sW1[NQ * EMBED];             // 40 KiB
    __shared__ float sCA[ROWS_PER_BLOCK][NQ];
    __shared__ float sSA[ROWS_PER_BLOCK][NQ];
    __shared__ float sEV[ROWS_PER_BLOCK][NQ];

    const int tid  = threadIdx.x;
    const int lane = tid & 63;
    const int wv   = tid >> 6;          // 0..3
    const int o    = lane & 15;         // k-slice lane
    const int g    = lane >> 4;         // row-pair group 0..3
    const int block0 = blockIdx.x * ROWS_PER_BLOCK;

    // ---- prefetch W2/b2 into registers NOW (used only in stage 3;
    //      latency hides under W1 staging + stage 1) ----
    float w2f[40];
    {
        const float4* w2v = (const float4*)(W2 + tid * 40);
        #pragma unroll
        for (int i = 0; i < 10; ++i) {
            float4 v = w2v[i];
            w2f[4*i+0] = v.x; w2f[4*i+1] = v.y; w2f[4*i+2] = v.z; w2f[4*i+3] = v.w;
        }
    }
    const float4 b2v = ((const float4*)b2)[tid];

    float b1r[NQ], qw0[NQ];
    #pragma unroll
    for (int w = 0; w < NQ; ++w) { qw0[w] = qw[w]; b1r[w] = b1[w]; }

    // ---- stage W1 into LDS (coalesced float4) ----
    {
        const float4* src = (const float4*)W1;
        float4* dst = (float4*)sW1;
        #pragma unroll
        for (int i = 0; i < 10; ++i) dst[tid + BLOCK * i] = src[tid + BLOCK * i];
    }
    __syncthreads();

    // ---------- stage 1: 8 rows per wave (2 per lane), 16 lanes per row ----
    {
        const int rloc0 = wv * 8 + g * 2;      // this lane's first row
        float acc0[NQ], acc1[NQ];
        #pragma unroll
        for (int q = 0; q < NQ; ++q) { acc0[q] = 0.f; acc1[q] = 0.f; }

        const float4* xr0 = (const float4*)(x + (size_t)(block0 + rloc0) * EMBED);
        const float4* xr1 = (const float4*)(x + (size_t)(block0 + rloc0 + 1) * EMBED);
        const float4* w1v = (const float4*)sW1;
        #pragma unroll 4
        for (int k = 0; k < 16; ++k) {
            const float4 xv0 = xr0[k * 16 + o];
            const float4 xv1 = xr1[k * 16 + o];
            #pragma unroll
            for (int q = 0; q < NQ; ++q) {
                const float4 wv4 = w1v[q * 256 + k * 16 + o];  // broadcast x4 groups
                acc0[q] = fmaf(xv0.x, wv4.x, acc0[q]);
                acc0[q] = fmaf(xv0.y, wv4.y, acc0[q]);
                acc0[q] = fmaf(xv0.z, wv4.z, acc0[q]);
                acc0[q] = fmaf(xv0.w, wv4.w, acc0[q]);
                acc1[q] = fmaf(xv1.x, wv4.x, acc1[q]);
                acc1[q] = fmaf(xv1.y, wv4.y, acc1[q]);
                acc1[q] = fmaf(xv1.z, wv4.z, acc1[q]);
                acc1[q] = fmaf(xv1.w, wv4.w, acc1[q]);
            }
        }
        // reduce across the 16 lanes of the group
        #pragma unroll
        for (int m = 1; m < 16; m <<= 1) {
            #pragma unroll
            for (int q = 0; q < NQ; ++q) {
                acc0[q] += __shfl_xor(acc0[q], m, 64);
                acc1[q] += __shfl_xor(acc1[q], m, 64);
            }
        }
        if (o == 0) {
            #pragma unroll
            for (int w = 0; w < NQ; ++w) {
                const float A0 = acc0[w] + b1r[w] + qw0[w];
                const float A1 = acc1[w] + b1r[w] + qw0[w];
                sCA[rloc0][w]     = __cosf(A0);
                sSA[rloc0][w]     = __sinf(A0);
                sCA[rloc0 + 1][w] = __cosf(A1);
                sSA[rloc0 + 1][w] = __sinf(A1);
            }
        }
    }

    __syncthreads();

    // ---------- closed-form ev: q's spread across all 4 waves ----------
    // filtered term counts: q0:16 q1:1 q2:1 q3:2 q4:2 q5:4 q6:4 q7:8 q8:8 q9:16
    if (lane < ROWS_PER_BLOCK) {
        const int row = lane;
        float ca[NQ], sa[NQ], cb[NQ], sb[NQ];
        #pragma unroll
        for (int w = 0; w < NQ; ++w) {
            ca[w] = sCA[row][w];
            sa[w] = sSA[row][w];
            const float B = qw[NQ + w];
            cb[w] = __cosf(B); sb[w] = __sinf(B);
        }
        #define EVQ(QC) do {                                                      \
            float ev = 0.f;                                                       \
            _Pragma("unroll")                                                     \
            for (int k = 0; k < TT.nt[QC]; ++k) {                                 \
                float P = TT.sg[QC][k];                                           \
                _Pragma("unroll")                                                 \
                for (int w = 0; w < NQ; ++w) {                                    \
                    if ((TT.vm[QC] >> w) & 1) P *= ((TT.tm[QC][k] >> w) & 1) ? sa[w] : ca[w]; \
                    if ((TT.um[QC] >> w) & 1) P *= ((TT.sm[QC][k] >> w) & 1) ? sb[w] : cb[w]; \
                }                                                                 \
                ev += P;                                                          \
            }                                                                     \
            sEV[row][QC] = ev;                                                    \
        } while (0)
        if      (wv == 0) { EVQ(0); }
        else if (wv == 1) { EVQ(9); }
        else if (wv == 2) { EVQ(7); EVQ(8); }
        else              { EVQ(1); EVQ(2); EVQ(3); EVQ(4); EVQ(5); EVQ(6); }
        #undef EVQ
    }

    __syncthreads();

    // ---------- stage 3: out[r][e] = b2[e] + sum_q ev[r][q]*W2[e][q] ----------
    #pragma unroll 4
    for (int r = 0; r < ROWS_PER_BLOCK; ++r) {
        float evr[NQ];
        #pragma unroll
        for (int q = 0; q < NQ; ++q) evr[q] = sEV[r][q];
        float o0 = b2v.x, o1 = b2v.y, o2 = b2v.z, o3 = b2v.w;
        #pragma unroll
        for (int q = 0; q < NQ; ++q) {
            o0 = fmaf(evr[q], w2f[ 0 + q], o0);
            o1 = fmaf(evr[q], w2f[10 + q], o1);
            o2 = fmaf(evr[q], w2f[20 + q], o2);
            o3 = fmaf(evr[q], w2f[30 + q], o3);
        }
        float4 ov = {o0, o1, o2, o3};
        ((float4*)(out + (size_t)(block0 + r) * EMBED))[tid] = ov;
    }
}

extern "C" void kernel_launch(void* const* d_in, const int* in_sizes, int n_in,
                              void* d_out, int out_size, void* d_ws, size_t ws_size,
                              hipStream_t stream) {
    (void)in_sizes; (void)n_in; (void)d_ws; (void)ws_size; (void)out_size;
    const float* x  = (const float*)d_in[0];
    const float* W1 = (const float*)d_in[1];
    const float* b1 = (const float*)d_in[2];
    const float* qw = (const float*)d_in[3];
    const float* W2 = (const float*)d_in[4];
    const float* b2 = (const float*)d_in[5];
    float* out = (float*)d_out;

    const int total_rows = 16 * 1024;
    dim3 grid(total_rows / ROWS_PER_BLOCK);   // 512 blocks, 3 resident/CU
    ffq_kernel<<<grid, BLOCK, 0, stream>>>(x, W1, b1, qw, W2, b2, out);
}

// Round 5
// 32.336 us; speedup vs baseline: 1.3388x; 1.3388x over previous
//
#include <hip/hip_runtime.h>

#define NQ 10
#define EMBED 1024
#define ROWS_PER_BLOCK 32
#define BLOCK 512            // 8 waves; each wave: 2 groups x 32 lanes, 2 rows/lane

// ---------------------------------------------------------------------------
// Closed-form ev (validated R1-R4, passing at absmax 2e-3):
// conjugate circuit by H^10 -> RX gates become diagonal phases, CNOT ring
// becomes reversed ring sigma.  <Z_q> collapses to a trig polynomial:
//   ev_q = sum_{S subset u_q, T=sigma^T S subset v_q} i^(|T|+|S|)
//          prod_{T} sinA prod_{v\T} cosA * prod_{S} sinB prod_{u\S} cosB
// Odd-parity terms are imaginary and cancel -> filtered at constexpr time.
// ---------------------------------------------------------------------------

constexpr int kPop(int x) { int c = 0; for (int i = 0; i < 10; ++i) c += (x >> i) & 1; return c; }

constexpr int sigma_map(int a) {
    int b = 0;
    for (int i = 0; i < 9; ++i) b |= (((a >> i) & 1) ^ ((a >> (i + 1)) & 1)) << i;
    b |= (((a >> 9) & 1) ^ ((a >> 0) & 1) ^ ((a >> 1) & 1)) << 9;
    return b;
}

#define MAXT 40
struct Terms {
    int nt[NQ];
    int vm[NQ];
    int um[NQ];
    unsigned short tm[NQ][MAXT];
    unsigned short sm[NQ][MAXT];
    float sg[NQ][MAXT];
};

constexpr Terms gen_terms() {
    Terms t{};
    int inv_e[NQ] = {};
    for (int a = 0; a < 1024; ++a) {
        const int s = sigma_map(a);
        for (int q = 0; q < NQ; ++q) if (s == (1 << q)) inv_e[q] = a;
    }
    for (int q = 0; q < NQ; ++q) {
        const int u = inv_e[q];
        int v = 0;
        for (int w = 0; w < NQ; ++w) if ((u >> w) & 1) v ^= inv_e[w];
        t.um[q] = u; t.vm[q] = v;
        int n = 0;
        int S = 0;
        while (true) {
            int T = (((S >> 0) ^ (S >> 9)) & 1)
                  | ((((S >> 0) ^ (S >> 1) ^ (S >> 9)) & 1) << 1);
            for (int j = 2; j < 10; ++j) T |= ((((S >> (j - 1)) ^ (S >> j)) & 1) << j);
            if ((T & ~v) == 0) {
                const int p = kPop(T) + kPop(S);
                if (!(p & 1)) {
                    t.tm[q][n] = (unsigned short)T;
                    t.sm[q][n] = (unsigned short)S;
                    t.sg[q][n] = (p & 2) ? -1.f : 1.f;
                    ++n;
                }
            }
            if (S == u) break;
            S = (S - u) & u;
        }
        t.nt[q] = n;
    }
    return t;
}

constexpr Terms TT = gen_terms();

extern "C" __global__ __launch_bounds__(BLOCK, 4)
void ffq_kernel(const float* __restrict__ x, const float* __restrict__ W1,
                const float* __restrict__ b1, const float* __restrict__ qw,
                const float* __restrict__ W2, const float* __restrict__ b2,
                float* __restrict__ out)
{
    __shared__ float sW1[NQ * EMBED];             // 40 KiB
    __shared__ float sCA[ROWS_PER_BLOCK][NQ];
    __shared__ float sSA[ROWS_PER_BLOCK][NQ];
    __shared__ float sEV[ROWS_PER_BLOCK][NQ];

    const int tid  = threadIdx.x;
    const int lane = tid & 63;
    const int wv   = tid >> 6;          // 0..7
    const int o    = lane & 31;         // k-slice lane within row
    const int g    = lane >> 5;         // group 0..1 (2 rows each)
    const int block0 = blockIdx.x * ROWS_PER_BLOCK;

    // ---- prefetch W2/b2 into registers (stage-3 data; hides under staging) --
    const int e4 = tid & 255;           // float4 column in stage 3
    float w2f[40];
    {
        const float4* w2v = (const float4*)(W2 + e4 * 40);
        #pragma unroll
        for (int i = 0; i < 10; ++i) {
            float4 v = w2v[i];
            w2f[4*i+0] = v.x; w2f[4*i+1] = v.y; w2f[4*i+2] = v.z; w2f[4*i+3] = v.w;
        }
    }
    const float4 b2v = ((const float4*)b2)[e4];

    float b1r[NQ], qw0[NQ];
    #pragma unroll
    for (int w = 0; w < NQ; ++w) { qw0[w] = qw[w]; b1r[w] = b1[w]; }

    // ---- stage W1 into LDS (coalesced float4) ----
    {
        const float4* src = (const float4*)W1;
        float4* dst = (float4*)sW1;
        #pragma unroll
        for (int i = 0; i < 5; ++i) dst[tid + BLOCK * i] = src[tid + BLOCK * i];
    }
    __syncthreads();

    // ---------- stage 1: 4 rows per wave (2 per lane), 32 lanes per row -----
    {
        const int rloc0 = wv * 4 + g * 2;      // this lane's first row
        float acc0[NQ], acc1[NQ];
        #pragma unroll
        for (int q = 0; q < NQ; ++q) { acc0[q] = 0.f; acc1[q] = 0.f; }

        const float4* xr0 = (const float4*)(x + (size_t)(block0 + rloc0) * EMBED);
        const float4* xr1 = (const float4*)(x + (size_t)(block0 + rloc0 + 1) * EMBED);
        const float4* w1v = (const float4*)sW1;
        #pragma unroll
        for (int k = 0; k < 8; ++k) {
            const float4 xv0 = xr0[k * 32 + o];
            const float4 xv1 = xr1[k * 32 + o];
            #pragma unroll
            for (int q = 0; q < NQ; ++q) {
                const float4 wv4 = w1v[q * 256 + k * 32 + o];  // broadcast x2 groups
                acc0[q] = fmaf(xv0.x, wv4.x, acc0[q]);
                acc0[q] = fmaf(xv0.y, wv4.y, acc0[q]);
                acc0[q] = fmaf(xv0.z, wv4.z, acc0[q]);
                acc0[q] = fmaf(xv0.w, wv4.w, acc0[q]);
                acc1[q] = fmaf(xv1.x, wv4.x, acc1[q]);
                acc1[q] = fmaf(xv1.y, wv4.y, acc1[q]);
                acc1[q] = fmaf(xv1.z, wv4.z, acc1[q]);
                acc1[q] = fmaf(xv1.w, wv4.w, acc1[q]);
            }
        }
        // reduce across the 32 lanes of the group (xor masks stay in-group)
        #pragma unroll
        for (int m = 1; m < 32; m <<= 1) {
            #pragma unroll
            for (int q = 0; q < NQ; ++q) {
                acc0[q] += __shfl_xor(acc0[q], m, 64);
                acc1[q] += __shfl_xor(acc1[q], m, 64);
            }
        }
        if (o == 0) {
            #pragma unroll
            for (int w = 0; w < NQ; ++w) {
                const float A0 = acc0[w] + b1r[w] + qw0[w];
                const float A1 = acc1[w] + b1r[w] + qw0[w];
                sCA[rloc0][w]     = __cosf(A0);
                sSA[rloc0][w]     = __sinf(A0);
                sCA[rloc0 + 1][w] = __cosf(A1);
                sSA[rloc0 + 1][w] = __sinf(A1);
            }
        }
    }

    __syncthreads();

    // ---------- closed-form ev: q's spread across 8 waves, 1 row per lane ---
    // filtered term counts: q0:16 q1:1 q2:1 q3:2 q4:2 q5:4 q6:4 q7:8 q8:8 q9:16
    if (lane < ROWS_PER_BLOCK) {
        const int row = lane;
        float ca[NQ], sa[NQ], cb[NQ], sb[NQ];
        #pragma unroll
        for (int w = 0; w < NQ; ++w) {
            ca[w] = sCA[row][w];
            sa[w] = sSA[row][w];
            const float B = qw[NQ + w];
            cb[w] = __cosf(B); sb[w] = __sinf(B);
        }
        #define EVQ(QC) do {                                                      \
            float ev = 0.f;                                                       \
            _Pragma("unroll")                                                     \
            for (int k = 0; k < TT.nt[QC]; ++k) {                                 \
                float P = TT.sg[QC][k];                                           \
                _Pragma("unroll")                                                 \
                for (int w = 0; w < NQ; ++w) {                                    \
                    if ((TT.vm[QC] >> w) & 1) P *= ((TT.tm[QC][k] >> w) & 1) ? sa[w] : ca[w]; \
                    if ((TT.um[QC] >> w) & 1) P *= ((TT.sm[QC][k] >> w) & 1) ? sb[w] : cb[w]; \
                }                                                                 \
                ev += P;                                                          \
            }                                                                     \
            sEV[row][QC] = ev;                                                    \
        } while (0)
        switch (wv) {
            case 0: EVQ(0); break;
            case 1: EVQ(9); break;
            case 2: EVQ(7); break;
            case 3: EVQ(8); break;
            case 4: EVQ(5); EVQ(6); break;
            case 5: EVQ(3); EVQ(4); break;
            case 6: EVQ(1); EVQ(2); break;
            default: break;              // wave 7 idle here
        }
        #undef EVQ
    }

    __syncthreads();

    // ---------- stage 3: out[r][e] = b2[e] + sum_q ev[r][q]*W2[e][q] ----------
    // 512 threads: e4 = tid&255 (float4 column), half = tid>>8 (16 rows each)
    const int r0 = (tid >> 8) * 16;
    #pragma unroll
    for (int r = 0; r < 16; ++r) {
        const int rr = r0 + r;
        float evr[NQ];
        #pragma unroll
        for (int q = 0; q < NQ; ++q) evr[q] = sEV[rr][q];
        float o0 = b2v.x, o1 = b2v.y, o2 = b2v.z, o3 = b2v.w;
        #pragma unroll
        for (int q = 0; q < NQ; ++q) {
            o0 = fmaf(evr[q], w2f[ 0 + q], o0);
            o1 = fmaf(evr[q], w2f[10 + q], o1);
            o2 = fmaf(evr[q], w2f[20 + q], o2);
            o3 = fmaf(evr[q], w2f[30 + q], o3);
        }
        float4 ov = {o0, o1, o2, o3};
        ((float4*)(out + (size_t)(block0 + rr) * EMBED))[e4] = ov;
    }
}

extern "C" void kernel_launch(void* const* d_in, const int* in_sizes, int n_in,
                              void* d_out, int out_size, void* d_ws, size_t ws_size,
                              hipStream_t stream) {
    (void)in_sizes; (void)n_in; (void)d_ws; (void)ws_size; (void)out_size;
    const float* x  = (const float*)d_in[0];
    const float* W1 = (const float*)d_in[1];
    const float* b1 = (const float*)d_in[2];
    const float* qw = (const float*)d_in[3];
    const float* W2 = (const float*)d_in[4];
    const float* b2 = (const float*)d_in[5];
    float* out = (float*)d_out;

    const int total_rows = 16 * 1024;
    dim3 grid(total_rows / ROWS_PER_BLOCK);   // 512 blocks, 2/CU, 16 waves/CU
    ffq_kernel<<<grid, BLOCK, 0, stream>>>(x, W1, b1, qw, W2, b2, out);
}